// Round 7
// baseline (1494.426 us; speedup 1.0000x reference)
//
#include <hip/hip_runtime.h>
#include <math.h>

// ---------------------------------------------------------------------------
// Com_CNN_RNN R6: data-as-flag pipelined chains + fused tail.
//  - k_pipe (64 WGs): WG 0-31 = e1-L0 (gi computed on the fly from emb rows,
//    Wih+Whh register-resident), WG 32-63 = e1-L1 skewed 1 step. Sync is
//    POISON-RETRY on the h data itself: |h|<1 strictly, so 2.0f is impossible;
//    hbuf pre-poisoned, producers fire relaxed sc1 stores (no drain, no flag),
//    consumers retry-load until non-poison. One barrier/step, double-buf LDS.
//  - k_tail (32 WGs): e2-L0, e2-L1, conv+maxpool(degenerate global max), rnn2,
//    head fused with the R3/R5 flag protocol (small, proven).
// ---------------------------------------------------------------------------

__device__ __forceinline__ float sigm(float x) { return 1.f / (1.f + expf(-x)); }

#define POISON_U32 0x40000000u   // 2.0f — unreachable for GRU h (|h|<1)

// LDS index map: p(k) = k + (k>>4)*4 (pad 4 words per 16; keeps float4 align)
#define LDSP(k) ((k) + (((k) >> 4) << 2))

__device__ __forceinline__ float red32(float v) {
    v += __shfl_xor(v, 16, 64);
    v += __shfl_xor(v, 8, 64);
    v += __shfl_xor(v, 4, 64);
    v += __shfl_xor(v, 2, 64);
    v += __shfl_xor(v, 1, 64);
    return v;
}

__device__ __forceinline__ void poll_ge(const unsigned int* p, unsigned tgt) {
    unsigned v;
    do {
        v = __hip_atomic_load(p, __ATOMIC_RELAXED, __HIP_MEMORY_SCOPE_AGENT);
        if (v < tgt) __builtin_amdgcn_s_sleep(1);
    } while (v < tgt);
}

// stage 4 floats (this thread's slice of 1024) with poison retry; idx = 0..255
__device__ __forceinline__ void stage4_poison(float* dstbase, const float* src,
                                              int idx) {
    const unsigned long long* sp = (const unsigned long long*)src + idx * 2;
    unsigned long long d0, d1;
    for (;;) {
        d0 = __hip_atomic_load(sp + 0, __ATOMIC_RELAXED, __HIP_MEMORY_SCOPE_AGENT);
        d1 = __hip_atomic_load(sp + 1, __ATOMIC_RELAXED, __HIP_MEMORY_SCOPE_AGENT);
        if ((unsigned)(d0 & 0xFFFFFFFFu) != POISON_U32 &&
            (unsigned)(d0 >> 32)         != POISON_U32 &&
            (unsigned)(d1 & 0xFFFFFFFFu) != POISON_U32 &&
            (unsigned)(d1 >> 32)         != POISON_U32) break;
        __builtin_amdgcn_s_sleep(1);
    }
    union { unsigned long long u; float2 f; } c0, c1;
    c0.u = d0; c1.u = d1;
    float* d = dstbase + LDSP(idx * 4);
    d[0] = c0.f.x; d[1] = c0.f.y; d[2] = c1.f.x; d[3] = c1.f.y;
}

// plain (non-polled) 1024-float stage, 256 threads
__device__ __forceinline__ void stage1024(float* dst, const float* src, int tid) {
    if (tid < 256) {
        const unsigned long long* s = (const unsigned long long*)src + tid * 2;
        unsigned long long d0 = __hip_atomic_load(s + 0, __ATOMIC_RELAXED,
                                                  __HIP_MEMORY_SCOPE_AGENT);
        unsigned long long d1 = __hip_atomic_load(s + 1, __ATOMIC_RELAXED,
                                                  __HIP_MEMORY_SCOPE_AGENT);
        union { unsigned long long u; float2 f; } c0, c1;
        c0.u = d0; c1.u = d1;
        float* d = dst + LDSP(tid * 4);
        d[0] = c0.f.x; d[1] = c0.f.y; d[2] = c1.f.x; d[3] = c1.f.y;
    }
}

__device__ __forceinline__ float gru1(float gr, float gz, float gn,
                                      float ar, float az, float an,
                                      const float bh[3], float hp) {
    float r = sigm(gr + ar + bh[0]);
    float z = sigm(gz + az + bh[1]);
    float n = tanhf(gn + r * (an + bh[2]));
    return (1.f - z) * n + z * hp;
}

// ---------------------------------------------------------------------------
// k_pipe: epoch-1 L0 + L1 pipelined, data-as-flag. grid 64 x 512.
// ---------------------------------------------------------------------------
__global__ __launch_bounds__(512, 1) void k_pipe(
    const float* __restrict__ Whh1, const float* __restrict__ bhh1,
    const float* __restrict__ Wih1, const float* __restrict__ bih1,
    const float* __restrict__ emb,
    const int* __restrict__ sentA, const int* __restrict__ sentB,
    float* __restrict__ e2x,              // [2 sent][2 layer][512]
    float* __restrict__ hbuf0,            // [257][2][512] poisoned t>=1
    float* __restrict__ hbuf1)            // [257][2][512] poisoned t>=1
{
    const int tid   = threadIdx.x;
    const int layer = blockIdx.x >> 5;    // 0 or 1
    const int wgi   = blockIdx.x & 31;
    const int grp   = tid >> 5;           // 0..15
    const int lane  = tid & 31;
    const int j     = wgi * 16 + grp;     // h row 0..511
    const int colbase = lane * 16;

    __shared__ float xl[2][1280];         // double-buffered x stage
    __shared__ float hl[2][1280];         // double-buffered own-layer h stage

    const size_t WS = (size_t)1536 * 512;
    const float* WH = Whh1 + (size_t)layer * WS;
    const float* WI = Wih1 + (size_t)layer * WS;

    // register-resident weights: Whh + Wih slices (3 gates x 16 cols each)
    float wh[3][16], wi[3][16];
#pragma unroll
    for (int q = 0; q < 3; ++q) {
        const float* srcH = WH + (size_t)(q * 512 + j) * 512 + colbase;
        const float* srcI = WI + (size_t)(q * 512 + j) * 512 + colbase;
#pragma unroll
        for (int c4 = 0; c4 < 4; ++c4) {
            float4 vH = *(const float4*)(srcH + c4 * 4);
            float4 vI = *(const float4*)(srcI + c4 * 4);
            wh[q][c4*4+0] = vH.x; wh[q][c4*4+1] = vH.y;
            wh[q][c4*4+2] = vH.z; wh[q][c4*4+3] = vH.w;
            wi[q][c4*4+0] = vI.x; wi[q][c4*4+1] = vI.y;
            wi[q][c4*4+2] = vI.z; wi[q][c4*4+3] = vI.w;
        }
    }
#pragma unroll
    for (int q = 0; q < 3; ++q)
#pragma unroll
        for (int c = 0; c < 16; ++c) {
            asm volatile("" : "+v"(wh[q][c]));
            asm volatile("" : "+v"(wi[q][c]));
        }

    float bh[3], bi[3];
#pragma unroll
    for (int q = 0; q < 3; ++q) {
        bh[q] = bhh1[layer * 1536 + q * 512 + j];
        bi[q] = bih1[layer * 1536 + q * 512 + j];
    }

    float* hout = (layer == 0) ? hbuf0 : hbuf1;
    float hprev[2] = {0.f, 0.f};

    for (int t = 1; t <= 256; ++t) {
        const int p = t & 1;

        // ---- stage x (tid<256) and own-layer h_{t-1} (tid>=256, t>1) ----
        if (tid < 256) {
            if (layer == 0) {
                const int i = tid * 4, s = i >> 9, k = i & 511;
                const int idx = s ? sentB[t - 1] : sentA[t - 1];
                float4 v = *(const float4*)(emb + (size_t)idx * 512 + k);
                float* d = &xl[p][LDSP(i)];
                d[0] = v.x; d[1] = v.y; d[2] = v.z; d[3] = v.w;
            } else {
                stage4_poison(xl[p], hbuf0 + (size_t)t * 1024, tid);
            }
        } else if (t > 1) {
            stage4_poison(hl[p], hout + (size_t)(t - 1) * 1024, tid - 256);
        }
        __syncthreads();

        // ---- dots: gi from x (wi), gh from h (wh) ----
        float aR[2] = {0.f,0.f}, aZ[2] = {0.f,0.f};
        float aGN[2] = {0.f,0.f}, aHN[2] = {0.f,0.f};
#pragma unroll
        for (int s = 0; s < 2; ++s) {
            const int base = s * 640 + 20 * lane;
#pragma unroll
            for (int c4 = 0; c4 < 4; ++c4) {
                float4 xv = *(const float4*)&xl[p][base + c4 * 4];
                aR[s]  += wi[0][c4*4+0]*xv.x + wi[0][c4*4+1]*xv.y
                        + wi[0][c4*4+2]*xv.z + wi[0][c4*4+3]*xv.w;
                aZ[s]  += wi[1][c4*4+0]*xv.x + wi[1][c4*4+1]*xv.y
                        + wi[1][c4*4+2]*xv.z + wi[1][c4*4+3]*xv.w;
                aGN[s] += wi[2][c4*4+0]*xv.x + wi[2][c4*4+1]*xv.y
                        + wi[2][c4*4+2]*xv.z + wi[2][c4*4+3]*xv.w;
            }
            if (t > 1) {
#pragma unroll
                for (int c4 = 0; c4 < 4; ++c4) {
                    float4 hv = *(const float4*)&hl[p][base + c4 * 4];
                    aR[s]  += wh[0][c4*4+0]*hv.x + wh[0][c4*4+1]*hv.y
                            + wh[0][c4*4+2]*hv.z + wh[0][c4*4+3]*hv.w;
                    aZ[s]  += wh[1][c4*4+0]*hv.x + wh[1][c4*4+1]*hv.y
                            + wh[1][c4*4+2]*hv.z + wh[1][c4*4+3]*hv.w;
                    aHN[s] += wh[2][c4*4+0]*hv.x + wh[2][c4*4+1]*hv.y
                            + wh[2][c4*4+2]*hv.z + wh[2][c4*4+3]*hv.w;
                }
            }
        }
#pragma unroll
        for (int s = 0; s < 2; ++s) {
            aR[s] = red32(aR[s]); aZ[s] = red32(aZ[s]);
            aGN[s] = red32(aGN[s]); aHN[s] = red32(aHN[s]);
        }

        float hn[2];
#pragma unroll
        for (int s = 0; s < 2; ++s) {
            float r = sigm(aR[s] + bi[0] + bh[0]);
            float z = sigm(aZ[s] + bi[1] + bh[1]);
            float n = tanhf(aGN[s] + bi[2] + r * (aHN[s] + bh[2]));
            hn[s] = (1.f - z) * n + z * hprev[s];
            hprev[s] = hn[s];
        }

        // publish: fire-and-forget relaxed sc1 (data IS the flag)
        if (lane == 0) {
#pragma unroll
            for (int s = 0; s < 2; ++s) {
                __hip_atomic_store(hout + (size_t)t * 1024 + s * 512 + j, hn[s],
                                   __ATOMIC_RELAXED, __HIP_MEMORY_SCOPE_AGENT);
                if (t == 256)
                    e2x[s * 1024 + layer * 512 + j] = hn[s];
            }
        }
        // no drain, no flag, no second barrier
    }
}

// ---------------------------------------------------------------------------
// k_tail: e2-L0 -> e2-L1 -> conv+pool -> rnn2 -> head, fused. grid 32 x 512.
// (R5's proven flag protocol.)
// ---------------------------------------------------------------------------
__global__ __launch_bounds__(512, 1) void k_tail(
    const float* __restrict__ Wih1, const float* __restrict__ bih1,
    const float* __restrict__ Whh1, const float* __restrict__ bhh1,
    const float* __restrict__ convw, const float* __restrict__ convb,
    const float* __restrict__ Whh2, const float* __restrict__ bhh2,
    const float* __restrict__ bih2, const float* __restrict__ Srow,
    const float* __restrict__ e2x,
    const float* __restrict__ WA, const float* __restrict__ WB,
    const float* __restrict__ b_bi, const float* __restrict__ Wlin,
    const float* __restrict__ blin,
    float* __restrict__ tb0, float* __restrict__ tb1, float* __restrict__ tr,
    float* __restrict__ Mmax,
    unsigned int* __restrict__ tctr, unsigned int* __restrict__ mf,
    float* __restrict__ outp)
{
    const int tid = threadIdx.x;
    const int wgi = blockIdx.x;
    const int grp = tid >> 5, lane = tid & 31;
    const int j = wgi * 16 + grp, colbase = lane * 16;
    const size_t WS = (size_t)1536 * 512;

    __shared__ float xlds[1280];
    __shared__ float hlds[1280];
    __shared__ float red[8];
    __shared__ float smax[4];

#define WAIT_ALL(val)  do { if (tid < 32) poll_ge(tctr + tid * 16, (unsigned)(val)); \
                            __syncthreads(); } while (0)
#define PUBLISH(val)   do { __builtin_amdgcn_s_waitcnt(0); __syncthreads(); \
                            if (tid == 0) __hip_atomic_store(tctr + wgi * 16, (unsigned)(val), \
                                __ATOMIC_RELAXED, __HIP_MEMORY_SCOPE_AGENT); } while (0)

    // -------- stage e2x into LDS (plain loads; written by previous dispatch)
    if (tid < 256) {
        const int i = tid * 4, s = i >> 9, k = i & 511;
        float4 v = *(const float4*)(e2x + s * 1024 + k);        // timestep 0
        float* d = xlds + LDSP(i);
        d[0] = v.x; d[1] = v.y; d[2] = v.z; d[3] = v.w;
    } else {
        const int i = (tid - 256) * 4, s = i >> 9, k = i & 511;
        float4 v = *(const float4*)(e2x + s * 1024 + 512 + k);  // timestep 1
        float* d = hlds + LDSP(i);
        d[0] = v.x; d[1] = v.y; d[2] = v.z; d[3] = v.w;
    }
    __syncthreads();

    // ================= stage A: e2-L0 =================
    float gp[2][2][3];   // [t][s][q]
    float bh[3], hp[2];
#pragma unroll
    for (int q = 0; q < 3; ++q) {
        const float* wp = Wih1 + (size_t)(q * 512 + j) * 512 + colbase;
        float w16[16];
#pragma unroll
        for (int c4 = 0; c4 < 4; ++c4) {
            float4 v = *(const float4*)(wp + c4 * 4);
            w16[c4*4+0] = v.x; w16[c4*4+1] = v.y; w16[c4*4+2] = v.z; w16[c4*4+3] = v.w;
        }
        float d00 = 0.f, d01 = 0.f, d10 = 0.f, d11 = 0.f;
#pragma unroll
        for (int c4 = 0; c4 < 4; ++c4) {
            float4 x0 = *(const float4*)&xlds[0 * 640 + 20 * lane + c4 * 4];
            float4 x1 = *(const float4*)&xlds[1 * 640 + 20 * lane + c4 * 4];
            float4 y0 = *(const float4*)&hlds[0 * 640 + 20 * lane + c4 * 4];
            float4 y1 = *(const float4*)&hlds[1 * 640 + 20 * lane + c4 * 4];
            d00 += w16[c4*4+0]*x0.x + w16[c4*4+1]*x0.y + w16[c4*4+2]*x0.z + w16[c4*4+3]*x0.w;
            d01 += w16[c4*4+0]*x1.x + w16[c4*4+1]*x1.y + w16[c4*4+2]*x1.z + w16[c4*4+3]*x1.w;
            d10 += w16[c4*4+0]*y0.x + w16[c4*4+1]*y0.y + w16[c4*4+2]*y0.z + w16[c4*4+3]*y0.w;
            d11 += w16[c4*4+0]*y1.x + w16[c4*4+1]*y1.y + w16[c4*4+2]*y1.z + w16[c4*4+3]*y1.w;
        }
        const float biq = bih1[q * 512 + j];
        gp[0][0][q] = red32(d00) + biq; gp[0][1][q] = red32(d01) + biq;
        gp[1][0][q] = red32(d10) + biq; gp[1][1][q] = red32(d11) + biq;
    }
#pragma unroll
    for (int q = 0; q < 3; ++q) bh[q] = bhh1[q * 512 + j];

    // step 1 (h0 = 0)
#pragma unroll
    for (int s = 0; s < 2; ++s)
        hp[s] = gru1(gp[0][s][0], gp[0][s][1], gp[0][s][2], 0.f, 0.f, 0.f, bh, 0.f);
    if (lane == 0)
#pragma unroll
        for (int s = 0; s < 2; ++s)
            __hip_atomic_store(tb0 + 1024 + s * 512 + j, hp[s],
                               __ATOMIC_RELAXED, __HIP_MEMORY_SCOPE_AGENT);
    PUBLISH(1);

    // step 2
    WAIT_ALL(1);
    stage1024(hlds, tb0 + 1024, tid);
    __syncthreads();
    {
        float wh3[3][16];
#pragma unroll
        for (int q = 0; q < 3; ++q) {
            const float* wp = Whh1 + (size_t)(q * 512 + j) * 512 + colbase;
#pragma unroll
            for (int c4 = 0; c4 < 4; ++c4) {
                float4 v = *(const float4*)(wp + c4 * 4);
                wh3[q][c4*4+0] = v.x; wh3[q][c4*4+1] = v.y;
                wh3[q][c4*4+2] = v.z; wh3[q][c4*4+3] = v.w;
            }
        }
        float acc[3][2] = {{0.f,0.f},{0.f,0.f},{0.f,0.f}};
#pragma unroll
        for (int s = 0; s < 2; ++s) {
            const int base = s * 640 + 20 * lane;
#pragma unroll
            for (int c4 = 0; c4 < 4; ++c4) {
                float4 hv = *(const float4*)&hlds[base + c4 * 4];
#pragma unroll
                for (int q = 0; q < 3; ++q)
                    acc[q][s] += wh3[q][c4*4+0]*hv.x + wh3[q][c4*4+1]*hv.y
                               + wh3[q][c4*4+2]*hv.z + wh3[q][c4*4+3]*hv.w;
            }
        }
#pragma unroll
        for (int s = 0; s < 2; ++s) {
            float a0 = red32(acc[0][s]), a1 = red32(acc[1][s]), a2 = red32(acc[2][s]);
            hp[s] = gru1(gp[1][s][0], gp[1][s][1], gp[1][s][2], a0, a1, a2, bh, hp[s]);
        }
        if (lane == 0)
#pragma unroll
            for (int s = 0; s < 2; ++s)
                __hip_atomic_store(tb0 + 2048 + s * 512 + j, hp[s],
                                   __ATOMIC_RELAXED, __HIP_MEMORY_SCOPE_AGENT);
        PUBLISH(2);
    }

    // ================= stage B: e2-L1 =================
    WAIT_ALL(2);
    stage1024(xlds, tb0 + 1024, tid);          // x step0 = L0 h1
    if (tid >= 256) {
        const int i = tid - 256;
        const unsigned long long* s = (const unsigned long long*)(tb0 + 2048) + i * 2;
        unsigned long long d0 = __hip_atomic_load(s + 0, __ATOMIC_RELAXED, __HIP_MEMORY_SCOPE_AGENT);
        unsigned long long d1 = __hip_atomic_load(s + 1, __ATOMIC_RELAXED, __HIP_MEMORY_SCOPE_AGENT);
        union { unsigned long long u; float2 f; } c0, c1; c0.u = d0; c1.u = d1;
        float* d = hlds + LDSP(i * 4);
        d[0] = c0.f.x; d[1] = c0.f.y; d[2] = c1.f.x; d[3] = c1.f.y;
    }
    __syncthreads();
#pragma unroll
    for (int q = 0; q < 3; ++q) {
        const float* wp = Wih1 + WS + (size_t)(q * 512 + j) * 512 + colbase;
        float w16[16];
#pragma unroll
        for (int c4 = 0; c4 < 4; ++c4) {
            float4 v = *(const float4*)(wp + c4 * 4);
            w16[c4*4+0] = v.x; w16[c4*4+1] = v.y; w16[c4*4+2] = v.z; w16[c4*4+3] = v.w;
        }
        float d00 = 0.f, d01 = 0.f, d10 = 0.f, d11 = 0.f;
#pragma unroll
        for (int c4 = 0; c4 < 4; ++c4) {
            float4 x0 = *(const float4*)&xlds[0 * 640 + 20 * lane + c4 * 4];
            float4 x1 = *(const float4*)&xlds[1 * 640 + 20 * lane + c4 * 4];
            float4 y0 = *(const float4*)&hlds[0 * 640 + 20 * lane + c4 * 4];
            float4 y1 = *(const float4*)&hlds[1 * 640 + 20 * lane + c4 * 4];
            d00 += w16[c4*4+0]*x0.x + w16[c4*4+1]*x0.y + w16[c4*4+2]*x0.z + w16[c4*4+3]*x0.w;
            d01 += w16[c4*4+0]*x1.x + w16[c4*4+1]*x1.y + w16[c4*4+2]*x1.z + w16[c4*4+3]*x1.w;
            d10 += w16[c4*4+0]*y0.x + w16[c4*4+1]*y0.y + w16[c4*4+2]*y0.z + w16[c4*4+3]*y0.w;
            d11 += w16[c4*4+0]*y1.x + w16[c4*4+1]*y1.y + w16[c4*4+2]*y1.z + w16[c4*4+3]*y1.w;
        }
        const float biq = bih1[1536 + q * 512 + j];
        gp[0][0][q] = red32(d00) + biq; gp[0][1][q] = red32(d01) + biq;
        gp[1][0][q] = red32(d10) + biq; gp[1][1][q] = red32(d11) + biq;
    }
#pragma unroll
    for (int q = 0; q < 3; ++q) bh[q] = bhh1[1536 + q * 512 + j];

#pragma unroll
    for (int s = 0; s < 2; ++s)
        hp[s] = gru1(gp[0][s][0], gp[0][s][1], gp[0][s][2], 0.f, 0.f, 0.f, bh, 0.f);
    if (lane == 0)
#pragma unroll
        for (int s = 0; s < 2; ++s)
            __hip_atomic_store(tb1 + 1024 + s * 512 + j, hp[s],
                               __ATOMIC_RELAXED, __HIP_MEMORY_SCOPE_AGENT);
    PUBLISH(3);

    WAIT_ALL(3);
    stage1024(hlds, tb1 + 1024, tid);
    __syncthreads();
    {
        float wh3[3][16];
#pragma unroll
        for (int q = 0; q < 3; ++q) {
            const float* wp = Whh1 + WS + (size_t)(q * 512 + j) * 512 + colbase;
#pragma unroll
            for (int c4 = 0; c4 < 4; ++c4) {
                float4 v = *(const float4*)(wp + c4 * 4);
                wh3[q][c4*4+0] = v.x; wh3[q][c4*4+1] = v.y;
                wh3[q][c4*4+2] = v.z; wh3[q][c4*4+3] = v.w;
            }
        }
        float acc[3][2] = {{0.f,0.f},{0.f,0.f},{0.f,0.f}};
#pragma unroll
        for (int s = 0; s < 2; ++s) {
            const int base = s * 640 + 20 * lane;
#pragma unroll
            for (int c4 = 0; c4 < 4; ++c4) {
                float4 hv = *(const float4*)&hlds[base + c4 * 4];
#pragma unroll
                for (int q = 0; q < 3; ++q)
                    acc[q][s] += wh3[q][c4*4+0]*hv.x + wh3[q][c4*4+1]*hv.y
                               + wh3[q][c4*4+2]*hv.z + wh3[q][c4*4+3]*hv.w;
            }
        }
#pragma unroll
        for (int s = 0; s < 2; ++s) {
            float a0 = red32(acc[0][s]), a1 = red32(acc[1][s]), a2 = red32(acc[2][s]);
            hp[s] = gru1(gp[1][s][0], gp[1][s][1], gp[1][s][2], a0, a1, a2, bh, hp[s]);
        }
        if (lane == 0)
#pragma unroll
            for (int s = 0; s < 2; ++s)
                __hip_atomic_store(tb1 + 2048 + s * 512 + j, hp[s],
                                   __ATOMIC_RELAXED, __HIP_MEMORY_SCOPE_AGENT);
        PUBLISH(4);
    }

    // ================= stage C: conv + global max pool =================
    WAIT_ALL(4);
    float m4[4];
    if (wgi == 0) {
        stage1024(xlds, tb0 + 2048, tid);          // finals L0 [2][512]
        if (tid >= 256) {
            const int i = tid - 256;
            const unsigned long long* s = (const unsigned long long*)(tb1 + 2048) + i * 2;
            unsigned long long d0 = __hip_atomic_load(s + 0, __ATOMIC_RELAXED, __HIP_MEMORY_SCOPE_AGENT);
            unsigned long long d1 = __hip_atomic_load(s + 1, __ATOMIC_RELAXED, __HIP_MEMORY_SCOPE_AGENT);
            union { unsigned long long u; float2 f; } c0, c1; c0.u = d0; c1.u = d1;
            float* d = hlds + LDSP(i * 4);
            d[0] = c0.f.x; d[1] = c0.f.y; d[2] = c1.f.x; d[3] = c1.f.y;
        }
        __syncthreads();
        for (int so = 0; so < 4; ++so) {
            const int s = so >> 1, o = so & 1;
            float acc = -3.4e38f;
            if (tid < 256) {
                acc = convb[o];
                const int base = 2 * tid - 255;
                for (int k = 0; k < 512; ++k) {
                    const int pos = base + k;
                    if ((unsigned)pos < 512u) {
                        const int gi0i = s * 512 + pos;
                        acc += xlds[LDSP(gi0i)] * convw[(size_t)(o * 2 + 0) * 512 + k]
                             + hlds[LDSP(gi0i)] * convw[(size_t)(o * 2 + 1) * 512 + k];
                    }
                }
            }
            float m = acc;
            m = fmaxf(m, __shfl_xor(m, 32, 64));
            m = fmaxf(m, __shfl_xor(m, 16, 64));
            m = fmaxf(m, __shfl_xor(m, 8, 64));
            m = fmaxf(m, __shfl_xor(m, 4, 64));
            m = fmaxf(m, __shfl_xor(m, 2, 64));
            m = fmaxf(m, __shfl_xor(m, 1, 64));
            if ((tid & 63) == 0) red[tid >> 6] = m;
            __syncthreads();
            if (tid == 0) {
                float mm = red[0];
                for (int i = 1; i < 8; ++i) mm = fmaxf(mm, red[i]);
                smax[so] = mm;
            }
            __syncthreads();
        }
        if (tid == 0) {
            for (int i = 0; i < 4; ++i)
                __hip_atomic_store(Mmax + i, smax[i],
                                   __ATOMIC_RELAXED, __HIP_MEMORY_SCOPE_AGENT);
            __builtin_amdgcn_s_waitcnt(0);
            __hip_atomic_store(mf, 1u, __ATOMIC_RELAXED, __HIP_MEMORY_SCOPE_AGENT);
        }
        __syncthreads();
#pragma unroll
        for (int i = 0; i < 4; ++i) m4[i] = smax[i];
    } else {
        if (tid == 0) poll_ge(mf, 1u);
        __syncthreads();
#pragma unroll
        for (int i = 0; i < 4; ++i)
            m4[i] = __hip_atomic_load((const float*)Mmax + i, __ATOMIC_RELAXED,
                                      __HIP_MEMORY_SCOPE_AGENT);
    }

    // ================= stage D: rnn2 (T=2, gi = Mmax*Srow + bih2) =================
    {
        float wh3[3][16];
#pragma unroll
        for (int q = 0; q < 3; ++q) {
            const float* wp = Whh2 + (size_t)(q * 512 + j) * 512 + colbase;
#pragma unroll
            for (int c4 = 0; c4 < 4; ++c4) {
                float4 v = *(const float4*)(wp + c4 * 4);
                wh3[q][c4*4+0] = v.x; wh3[q][c4*4+1] = v.y;
                wh3[q][c4*4+2] = v.z; wh3[q][c4*4+3] = v.w;
            }
        }
#pragma unroll
        for (int q = 0; q < 3; ++q) {
            const float sq = Srow[q * 512 + j];
            const float biq = bih2[q * 512 + j];
#pragma unroll
            for (int s = 0; s < 2; ++s) {
                gp[0][s][q] = m4[s * 2 + 0] * sq + biq;
                gp[1][s][q] = m4[s * 2 + 1] * sq + biq;
            }
            bh[q] = bhh2[q * 512 + j];
        }
#pragma unroll
        for (int s = 0; s < 2; ++s)
            hp[s] = gru1(gp[0][s][0], gp[0][s][1], gp[0][s][2], 0.f, 0.f, 0.f, bh, 0.f);
        if (lane == 0)
#pragma unroll
            for (int s = 0; s < 2; ++s)
                __hip_atomic_store(tr + 1024 + s * 512 + j, hp[s],
                                   __ATOMIC_RELAXED, __HIP_MEMORY_SCOPE_AGENT);
        PUBLISH(5);

        WAIT_ALL(5);
        stage1024(hlds, tr + 1024, tid);
        __syncthreads();
        float acc[3][2] = {{0.f,0.f},{0.f,0.f},{0.f,0.f}};
#pragma unroll
        for (int s = 0; s < 2; ++s) {
            const int base = s * 640 + 20 * lane;
#pragma unroll
            for (int c4 = 0; c4 < 4; ++c4) {
                float4 hv = *(const float4*)&hlds[base + c4 * 4];
#pragma unroll
                for (int q = 0; q < 3; ++q)
                    acc[q][s] += wh3[q][c4*4+0]*hv.x + wh3[q][c4*4+1]*hv.y
                               + wh3[q][c4*4+2]*hv.z + wh3[q][c4*4+3]*hv.w;
            }
        }
#pragma unroll
        for (int s = 0; s < 2; ++s) {
            float a0 = red32(acc[0][s]), a1 = red32(acc[1][s]), a2 = red32(acc[2][s]);
            hp[s] = gru1(gp[1][s][0], gp[1][s][1], gp[1][s][2], a0, a1, a2, bh, hp[s]);
        }
        if (lane == 0)
#pragma unroll
            for (int s = 0; s < 2; ++s)
                __hip_atomic_store(tr + 2048 + s * 512 + j, hp[s],
                                   __ATOMIC_RELAXED, __HIP_MEMORY_SCOPE_AGENT);
        PUBLISH(6);
    }

    // ================= stage E: similarity head (WG0 only) =================
    WAIT_ALL(6);
    if (wgi != 0) return;
    stage1024(xlds, tr + 2048, tid);          // hA = [0..511], hB = [512..1023]
    __syncthreads();
    float v = 0.f;
    if (tid < 256) {
        float acc = b_bi[tid];
        for (int jj = 0; jj < 512; ++jj) {
            const float a = xlds[LDSP(jj)];
            const float b = xlds[LDSP(512 + jj)];
            acc += (a * b) * WA[(size_t)jj * 256 + tid]
                 + fabsf(a - b) * WB[(size_t)jj * 256 + tid];
        }
        v = tanhf(acc) * Wlin[tid];
    }
    v += __shfl_xor(v, 32, 64);
    v += __shfl_xor(v, 16, 64);
    v += __shfl_xor(v, 8, 64);
    v += __shfl_xor(v, 4, 64);
    v += __shfl_xor(v, 2, 64);
    v += __shfl_xor(v, 1, 64);
    if ((tid & 63) == 0) red[tid >> 6] = v;
    __syncthreads();
    if (tid == 0) {
        float ssum = blin[0];
        for (int i = 0; i < 8; ++i) ssum += red[i];
        outp[0] = 1.f / (1.f + expf(-ssum));
    }
#undef WAIT_ALL
#undef PUBLISH
}

// ---------------------------------------------------------------------------
// init: Srow[r] = sum_k Wih2[r][k] (k<128); poison-fill hbuf0|hbuf1 (t=0 -> 0);
// zero tail flags (tctr 512 + mf 16).
// ---------------------------------------------------------------------------
__global__ __launch_bounds__(256) void k_init(
    const float* __restrict__ Wih2, float* __restrict__ Srow,
    unsigned int* __restrict__ hbufs,    // 2 x 257*1024 contiguous
    unsigned int* __restrict__ flags)    // 528 u32
{
    const int g = blockIdx.x * 256 + threadIdx.x;
    if (g < 1536) {
        float s = 0.f;
        for (int k = 0; k < 128; ++k) s += Wih2[(size_t)g * 128 + k];
        Srow[g] = s;
    }
    const int NBIG = 257 * 1024;
    const int NTOT = 2 * NBIG;
    for (int i = g; i < NTOT; i += gridDim.x * 256) {
        const int off = (i < NBIG) ? i : i - NBIG;
        hbufs[i] = (off < 1024) ? 0u : POISON_U32;
    }
    if (g < 528) flags[g] = 0u;
}

// ---------------------------------------------------------------------------
extern "C" void kernel_launch(void* const* d_in, const int* in_sizes, int n_in,
                              void* d_out, int out_size, void* d_ws, size_t ws_size,
                              hipStream_t stream)
{
    const int*   sentA = (const int*)d_in[0];
    const int*   sentB = (const int*)d_in[1];
    const float* emb   = (const float*)d_in[2];
    const float* Wih1  = (const float*)d_in[3];   // [2][1536][512]
    const float* Whh1  = (const float*)d_in[4];   // [2][1536][512]
    const float* bih1  = (const float*)d_in[5];   // [2][1536]
    const float* bhh1  = (const float*)d_in[6];   // [2][1536]
    const float* convw = (const float*)d_in[7];   // [2][2][512]
    const float* convb = (const float*)d_in[8];   // [2]
    const float* Wih2  = (const float*)d_in[9];   // [1536][128]
    const float* Whh2  = (const float*)d_in[10];  // [1536][512]
    const float* bih2  = (const float*)d_in[11];  // [1536]
    const float* bhh2  = (const float*)d_in[12];  // [1536]
    const float* WA    = (const float*)d_in[13];  // [512][256]
    const float* WB    = (const float*)d_in[14];  // [512][256]
    const float* b_bi  = (const float*)d_in[15];  // [256]
    const float* Wlin  = (const float*)d_in[16];  // [1][256]
    const float* blin  = (const float*)d_in[17];  // [1]

    float* ws = (float*)d_ws;
    size_t off = 0;
    float* e2x    = ws + off; off += 2048;        // [2 sent][2 layer][512]
    float* hbuf0  = ws + off; off += 257 * 1024;
    float* hbuf1  = ws + off; off += 257 * 1024;
    float* tb0    = ws + off; off += 3 * 1024;
    float* tb1    = ws + off; off += 3 * 1024;
    float* tr     = ws + off; off += 3 * 1024;
    float* Mmax   = ws + off; off += 16;
    float* Srow   = ws + off; off += 1536;
    unsigned int* flags = (unsigned int*)(ws + off);  // 528 u32
    unsigned int* tctr = flags;
    unsigned int* mf   = flags + 512;

    k_init<<<256, 256, 0, stream>>>(Wih2, Srow, (unsigned int*)hbuf0, flags);

    k_pipe<<<64, 512, 0, stream>>>(Whh1, bhh1, Wih1, bih1, emb, sentA, sentB,
                                   e2x, hbuf0, hbuf1);

    k_tail<<<32, 512, 0, stream>>>(Wih1, bih1, Whh1, bhh1, convw, convb,
                                   Whh2, bhh2, bih2, Srow, e2x,
                                   WA, WB, b_bi, Wlin, blin,
                                   tb0, tb1, tr, Mmax, tctr, mf, (float*)d_out);
}

// Round 8
// 1428.131 us; speedup vs baseline: 1.0464x; 1.0464x over previous
//
#include <hip/hip_runtime.h>
#include <math.h>

// ---------------------------------------------------------------------------
// Com_CNN_RNN R7: R5's proven flag-protocol pipeline, L0 gi on the fly.
//  - k_pipe (64 WGs x 512): WG 0-31 = e1-L0 (x = emb rows, no poll for x),
//    WG 32-63 = e1-L1 skewed 1 step (x = L0's h, flag-polled). Both layers
//    hold Wih+Whh slices register-resident (96 floats/thread, VGPR~120).
//    Sync: relaxed sc1 data stores -> vmcnt drain -> barrier -> per-WG flag
//    line; consumers poll flags with s_sleep backoff. (R4/R6 data-as-flag
//    regressed: the retry loop collapses VGPR to 96 and evicts weights.)
//  - k_tail (32 WGs): e2-L0, e2-L1, conv+maxpool(global max), rnn2, head.
// ---------------------------------------------------------------------------

__device__ __forceinline__ float sigm(float x) { return 1.f / (1.f + expf(-x)); }

// LDS index map: p(k) = k + (k>>4)*4 (pad 4 words per 16; keeps float4 align)
#define LDSP(k) ((k) + (((k) >> 4) << 2))

__device__ __forceinline__ float red32(float v) {
    v += __shfl_xor(v, 16, 64);
    v += __shfl_xor(v, 8, 64);
    v += __shfl_xor(v, 4, 64);
    v += __shfl_xor(v, 2, 64);
    v += __shfl_xor(v, 1, 64);
    return v;
}

__device__ __forceinline__ void poll_ge(const unsigned int* p, unsigned tgt) {
    unsigned v;
    do {
        v = __hip_atomic_load(p, __ATOMIC_RELAXED, __HIP_MEMORY_SCOPE_AGENT);
        if (v < tgt) __builtin_amdgcn_s_sleep(1);
    } while (v < tgt);
}

// 256 threads stage 1024 floats global->LDS via 8B LLC loads (caller barriers)
__device__ __forceinline__ void stage1024(float* dst, const float* src, int tid) {
    if (tid < 256) {
        const unsigned long long* s = (const unsigned long long*)src + tid * 2;
        unsigned long long d0 = __hip_atomic_load(s + 0, __ATOMIC_RELAXED,
                                                  __HIP_MEMORY_SCOPE_AGENT);
        unsigned long long d1 = __hip_atomic_load(s + 1, __ATOMIC_RELAXED,
                                                  __HIP_MEMORY_SCOPE_AGENT);
        union { unsigned long long u; float2 f; } c0, c1;
        c0.u = d0; c1.u = d1;
        float* d = dst + LDSP(tid * 4);
        d[0] = c0.f.x; d[1] = c0.f.y; d[2] = c1.f.x; d[3] = c1.f.y;
    }
}

__device__ __forceinline__ float gru1(float gr, float gz, float gn,
                                      float ar, float az, float an,
                                      const float bh[3], float hp) {
    float r = sigm(gr + ar + bh[0]);
    float z = sigm(gz + az + bh[1]);
    float n = tanhf(gn + r * (an + bh[2]));
    return (1.f - z) * n + z * hp;
}

// ---------------------------------------------------------------------------
// k_pipe: epoch-1 L0 + L1 pipelined, flag protocol. grid 64 x 512.
// ---------------------------------------------------------------------------
__global__ __launch_bounds__(512, 1) void k_pipe(
    const float* __restrict__ Whh1, const float* __restrict__ bhh1,
    const float* __restrict__ Wih1, const float* __restrict__ bih1,
    const float* __restrict__ emb,
    const int* __restrict__ sentA, const int* __restrict__ sentB,
    float* __restrict__ e2x,              // [2 sent][2 layer][512]
    float* __restrict__ hbuf0,            // [257][2][512]
    float* __restrict__ hbuf1,            // [257][2][512]
    unsigned int* __restrict__ fL0,       // [32][16]
    unsigned int* __restrict__ fL1)       // [32][16]
{
    const int tid   = threadIdx.x;
    const int layer = blockIdx.x >> 5;    // 0 or 1
    const int wgi   = blockIdx.x & 31;
    const int grp   = tid >> 5;           // 0..15
    const int lane  = tid & 31;
    const int j     = wgi * 16 + grp;     // h row 0..511
    const int colbase = lane * 16;

    __shared__ float xlds[1280];          // x_t stage (emb row or L0 h)
    __shared__ float hlds[1280];          // own-layer h_{t-1} stage

    const size_t WS = (size_t)1536 * 512;
    const float* WH = Whh1 + (size_t)layer * WS;
    const float* WI = Wih1 + (size_t)layer * WS;

    // register-resident weights: Whh + Wih slices (3 gates x 16 cols each)
    float wh[3][16], wi[3][16];
#pragma unroll
    for (int q = 0; q < 3; ++q) {
        const float* srcH = WH + (size_t)(q * 512 + j) * 512 + colbase;
        const float* srcI = WI + (size_t)(q * 512 + j) * 512 + colbase;
#pragma unroll
        for (int c4 = 0; c4 < 4; ++c4) {
            float4 vH = *(const float4*)(srcH + c4 * 4);
            float4 vI = *(const float4*)(srcI + c4 * 4);
            wh[q][c4*4+0] = vH.x; wh[q][c4*4+1] = vH.y;
            wh[q][c4*4+2] = vH.z; wh[q][c4*4+3] = vH.w;
            wi[q][c4*4+0] = vI.x; wi[q][c4*4+1] = vI.y;
            wi[q][c4*4+2] = vI.z; wi[q][c4*4+3] = vI.w;
        }
    }
#pragma unroll
    for (int q = 0; q < 3; ++q)
#pragma unroll
        for (int c = 0; c < 16; ++c) {
            asm volatile("" : "+v"(wh[q][c]));
            asm volatile("" : "+v"(wi[q][c]));
        }

    float bh[3], bi[3];
#pragma unroll
    for (int q = 0; q < 3; ++q) {
        bh[q] = bhh1[layer * 1536 + q * 512 + j];
        bi[q] = bih1[layer * 1536 + q * 512 + j];
    }

    float* hout = (layer == 0) ? hbuf0 : hbuf1;
    unsigned int* myflag = ((layer == 0) ? fL0 : fL1) + wgi * 16;
    float hprev[2] = {0.f, 0.f};

    for (int t = 1; t <= 256; ++t) {
        // ---- polls ----
        if (layer == 0) {
            if (t > 1 && tid < 32) poll_ge(fL0 + tid * 16, (unsigned)(t - 1));
        } else {
            if (tid < 32) poll_ge(fL0 + tid * 16, (unsigned)t);
            else if (t > 1 && tid >= 64 && tid < 96)
                poll_ge(fL1 + (tid - 64) * 16, (unsigned)(t - 1));
        }
        __syncthreads();

        // ---- stage x_t (tid<256) and own-layer h_{t-1} (tid>=256) ----
        if (tid < 256) {
            if (layer == 0) {
                const int i = tid * 4, s = i >> 9, k = i & 511;
                const int idx = s ? sentB[t - 1] : sentA[t - 1];
                float4 v = *(const float4*)(emb + (size_t)idx * 512 + k);
                float* d = &xlds[LDSP(i)];
                d[0] = v.x; d[1] = v.y; d[2] = v.z; d[3] = v.w;
            } else {
                stage1024(xlds, hbuf0 + (size_t)t * 1024, tid);
            }
        } else if (t > 1) {
            const int i = tid - 256;
            const unsigned long long* s =
                (const unsigned long long*)(hout + (size_t)(t - 1) * 1024) + i * 2;
            unsigned long long d0 = __hip_atomic_load(s + 0, __ATOMIC_RELAXED,
                                                      __HIP_MEMORY_SCOPE_AGENT);
            unsigned long long d1 = __hip_atomic_load(s + 1, __ATOMIC_RELAXED,
                                                      __HIP_MEMORY_SCOPE_AGENT);
            union { unsigned long long u; float2 f; } c0, c1;
            c0.u = d0; c1.u = d1;
            float* d = hlds + LDSP(i * 4);
            d[0] = c0.f.x; d[1] = c0.f.y; d[2] = c1.f.x; d[3] = c1.f.y;
        }
        __syncthreads();

        // ---- dots: gi from x (wi), gh from h (wh) ----
        float aR[2] = {0.f,0.f}, aZ[2] = {0.f,0.f};
        float aGN[2] = {0.f,0.f}, aHN[2] = {0.f,0.f};
#pragma unroll
        for (int s = 0; s < 2; ++s) {
            const int base = s * 640 + 20 * lane;
#pragma unroll
            for (int c4 = 0; c4 < 4; ++c4) {
                float4 xv = *(const float4*)&xlds[base + c4 * 4];
                aR[s]  += wi[0][c4*4+0]*xv.x + wi[0][c4*4+1]*xv.y
                        + wi[0][c4*4+2]*xv.z + wi[0][c4*4+3]*xv.w;
                aZ[s]  += wi[1][c4*4+0]*xv.x + wi[1][c4*4+1]*xv.y
                        + wi[1][c4*4+2]*xv.z + wi[1][c4*4+3]*xv.w;
                aGN[s] += wi[2][c4*4+0]*xv.x + wi[2][c4*4+1]*xv.y
                        + wi[2][c4*4+2]*xv.z + wi[2][c4*4+3]*xv.w;
            }
            if (t > 1) {
#pragma unroll
                for (int c4 = 0; c4 < 4; ++c4) {
                    float4 hv = *(const float4*)&hlds[base + c4 * 4];
                    aR[s]  += wh[0][c4*4+0]*hv.x + wh[0][c4*4+1]*hv.y
                            + wh[0][c4*4+2]*hv.z + wh[0][c4*4+3]*hv.w;
                    aZ[s]  += wh[1][c4*4+0]*hv.x + wh[1][c4*4+1]*hv.y
                            + wh[1][c4*4+2]*hv.z + wh[1][c4*4+3]*hv.w;
                    aHN[s] += wh[2][c4*4+0]*hv.x + wh[2][c4*4+1]*hv.y
                            + wh[2][c4*4+2]*hv.z + wh[2][c4*4+3]*hv.w;
                }
            }
        }
#pragma unroll
        for (int s = 0; s < 2; ++s) {
            aR[s] = red32(aR[s]); aZ[s] = red32(aZ[s]);
            aGN[s] = red32(aGN[s]); aHN[s] = red32(aHN[s]);
        }

        float hn[2];
#pragma unroll
        for (int s = 0; s < 2; ++s) {
            float r = sigm(aR[s] + bi[0] + bh[0]);
            float z = sigm(aZ[s] + bi[1] + bh[1]);
            float n = tanhf(aGN[s] + bi[2] + r * (aHN[s] + bh[2]));
            hn[s] = (1.f - z) * n + z * hprev[s];
            hprev[s] = hn[s];
        }

        if (lane == 0) {
#pragma unroll
            for (int s = 0; s < 2; ++s) {
                __hip_atomic_store(hout + (size_t)t * 1024 + s * 512 + j, hn[s],
                                   __ATOMIC_RELAXED, __HIP_MEMORY_SCOPE_AGENT);
                if (t == 256)
                    e2x[s * 1024 + layer * 512 + j] = hn[s];
            }
        }
        __builtin_amdgcn_s_waitcnt(0);   // this wave's h stores are in the LLC
        __syncthreads();                 // -> all waves' stores are
        if (tid == 0)
            __hip_atomic_store(myflag, (unsigned)t,
                               __ATOMIC_RELAXED, __HIP_MEMORY_SCOPE_AGENT);
    }
}

// ---------------------------------------------------------------------------
// k_tail: e2-L0 -> e2-L1 -> conv+pool -> rnn2 -> head, fused. grid 32 x 512.
// ---------------------------------------------------------------------------
__global__ __launch_bounds__(512, 1) void k_tail(
    const float* __restrict__ Wih1, const float* __restrict__ bih1,
    const float* __restrict__ Whh1, const float* __restrict__ bhh1,
    const float* __restrict__ convw, const float* __restrict__ convb,
    const float* __restrict__ Whh2, const float* __restrict__ bhh2,
    const float* __restrict__ bih2, const float* __restrict__ Srow,
    const float* __restrict__ e2x,
    const float* __restrict__ WA, const float* __restrict__ WB,
    const float* __restrict__ b_bi, const float* __restrict__ Wlin,
    const float* __restrict__ blin,
    float* __restrict__ tb0, float* __restrict__ tb1, float* __restrict__ tr,
    float* __restrict__ Mmax,
    unsigned int* __restrict__ tctr, unsigned int* __restrict__ mf,
    float* __restrict__ outp)
{
    const int tid = threadIdx.x;
    const int wgi = blockIdx.x;
    const int grp = tid >> 5, lane = tid & 31;
    const int j = wgi * 16 + grp, colbase = lane * 16;
    const size_t WS = (size_t)1536 * 512;

    __shared__ float xlds[1280];
    __shared__ float hlds[1280];
    __shared__ float red[8];
    __shared__ float smax[4];

#define WAIT_ALL(val)  do { if (tid < 32) poll_ge(tctr + tid * 16, (unsigned)(val)); \
                            __syncthreads(); } while (0)
#define PUBLISH(val)   do { __builtin_amdgcn_s_waitcnt(0); __syncthreads(); \
                            if (tid == 0) __hip_atomic_store(tctr + wgi * 16, (unsigned)(val), \
                                __ATOMIC_RELAXED, __HIP_MEMORY_SCOPE_AGENT); } while (0)

    // -------- stage e2x into LDS (plain loads; written by previous dispatch)
    if (tid < 256) {
        const int i = tid * 4, s = i >> 9, k = i & 511;
        float4 v = *(const float4*)(e2x + s * 1024 + k);        // timestep 0
        float* d = xlds + LDSP(i);
        d[0] = v.x; d[1] = v.y; d[2] = v.z; d[3] = v.w;
    } else {
        const int i = (tid - 256) * 4, s = i >> 9, k = i & 511;
        float4 v = *(const float4*)(e2x + s * 1024 + 512 + k);  // timestep 1
        float* d = hlds + LDSP(i);
        d[0] = v.x; d[1] = v.y; d[2] = v.z; d[3] = v.w;
    }
    __syncthreads();

    // ================= stage A: e2-L0 =================
    float gp[2][2][3];   // [t][s][q]
    float bh[3], hp[2];
#pragma unroll
    for (int q = 0; q < 3; ++q) {
        const float* wp = Wih1 + (size_t)(q * 512 + j) * 512 + colbase;
        float w16[16];
#pragma unroll
        for (int c4 = 0; c4 < 4; ++c4) {
            float4 v = *(const float4*)(wp + c4 * 4);
            w16[c4*4+0] = v.x; w16[c4*4+1] = v.y; w16[c4*4+2] = v.z; w16[c4*4+3] = v.w;
        }
        float d00 = 0.f, d01 = 0.f, d10 = 0.f, d11 = 0.f;
#pragma unroll
        for (int c4 = 0; c4 < 4; ++c4) {
            float4 x0 = *(const float4*)&xlds[0 * 640 + 20 * lane + c4 * 4];
            float4 x1 = *(const float4*)&xlds[1 * 640 + 20 * lane + c4 * 4];
            float4 y0 = *(const float4*)&hlds[0 * 640 + 20 * lane + c4 * 4];
            float4 y1 = *(const float4*)&hlds[1 * 640 + 20 * lane + c4 * 4];
            d00 += w16[c4*4+0]*x0.x + w16[c4*4+1]*x0.y + w16[c4*4+2]*x0.z + w16[c4*4+3]*x0.w;
            d01 += w16[c4*4+0]*x1.x + w16[c4*4+1]*x1.y + w16[c4*4+2]*x1.z + w16[c4*4+3]*x1.w;
            d10 += w16[c4*4+0]*y0.x + w16[c4*4+1]*y0.y + w16[c4*4+2]*y0.z + w16[c4*4+3]*y0.w;
            d11 += w16[c4*4+0]*y1.x + w16[c4*4+1]*y1.y + w16[c4*4+2]*y1.z + w16[c4*4+3]*y1.w;
        }
        const float biq = bih1[q * 512 + j];
        gp[0][0][q] = red32(d00) + biq; gp[0][1][q] = red32(d01) + biq;
        gp[1][0][q] = red32(d10) + biq; gp[1][1][q] = red32(d11) + biq;
    }
#pragma unroll
    for (int q = 0; q < 3; ++q) bh[q] = bhh1[q * 512 + j];

    // step 1 (h0 = 0)
#pragma unroll
    for (int s = 0; s < 2; ++s)
        hp[s] = gru1(gp[0][s][0], gp[0][s][1], gp[0][s][2], 0.f, 0.f, 0.f, bh, 0.f);
    if (lane == 0)
#pragma unroll
        for (int s = 0; s < 2; ++s)
            __hip_atomic_store(tb0 + 1024 + s * 512 + j, hp[s],
                               __ATOMIC_RELAXED, __HIP_MEMORY_SCOPE_AGENT);
    PUBLISH(1);

    // step 2
    WAIT_ALL(1);
    stage1024(hlds, tb0 + 1024, tid);
    __syncthreads();
    {
        float wh3[3][16];
#pragma unroll
        for (int q = 0; q < 3; ++q) {
            const float* wp = Whh1 + (size_t)(q * 512 + j) * 512 + colbase;
#pragma unroll
            for (int c4 = 0; c4 < 4; ++c4) {
                float4 v = *(const float4*)(wp + c4 * 4);
                wh3[q][c4*4+0] = v.x; wh3[q][c4*4+1] = v.y;
                wh3[q][c4*4+2] = v.z; wh3[q][c4*4+3] = v.w;
            }
        }
        float acc[3][2] = {{0.f,0.f},{0.f,0.f},{0.f,0.f}};
#pragma unroll
        for (int s = 0; s < 2; ++s) {
            const int base = s * 640 + 20 * lane;
#pragma unroll
            for (int c4 = 0; c4 < 4; ++c4) {
                float4 hv = *(const float4*)&hlds[base + c4 * 4];
#pragma unroll
                for (int q = 0; q < 3; ++q)
                    acc[q][s] += wh3[q][c4*4+0]*hv.x + wh3[q][c4*4+1]*hv.y
                               + wh3[q][c4*4+2]*hv.z + wh3[q][c4*4+3]*hv.w;
            }
        }
#pragma unroll
        for (int s = 0; s < 2; ++s) {
            float a0 = red32(acc[0][s]), a1 = red32(acc[1][s]), a2 = red32(acc[2][s]);
            hp[s] = gru1(gp[1][s][0], gp[1][s][1], gp[1][s][2], a0, a1, a2, bh, hp[s]);
        }
        if (lane == 0)
#pragma unroll
            for (int s = 0; s < 2; ++s)
                __hip_atomic_store(tb0 + 2048 + s * 512 + j, hp[s],
                                   __ATOMIC_RELAXED, __HIP_MEMORY_SCOPE_AGENT);
        PUBLISH(2);
    }

    // ================= stage B: e2-L1 =================
    WAIT_ALL(2);
    stage1024(xlds, tb0 + 1024, tid);          // x step0 = L0 h1
    if (tid >= 256) {
        const int i = tid - 256;
        const unsigned long long* s = (const unsigned long long*)(tb0 + 2048) + i * 2;
        unsigned long long d0 = __hip_atomic_load(s + 0, __ATOMIC_RELAXED, __HIP_MEMORY_SCOPE_AGENT);
        unsigned long long d1 = __hip_atomic_load(s + 1, __ATOMIC_RELAXED, __HIP_MEMORY_SCOPE_AGENT);
        union { unsigned long long u; float2 f; } c0, c1; c0.u = d0; c1.u = d1;
        float* d = hlds + LDSP(i * 4);
        d[0] = c0.f.x; d[1] = c0.f.y; d[2] = c1.f.x; d[3] = c1.f.y;
    }
    __syncthreads();
#pragma unroll
    for (int q = 0; q < 3; ++q) {
        const float* wp = Wih1 + WS + (size_t)(q * 512 + j) * 512 + colbase;
        float w16[16];
#pragma unroll
        for (int c4 = 0; c4 < 4; ++c4) {
            float4 v = *(const float4*)(wp + c4 * 4);
            w16[c4*4+0] = v.x; w16[c4*4+1] = v.y; w16[c4*4+2] = v.z; w16[c4*4+3] = v.w;
        }
        float d00 = 0.f, d01 = 0.f, d10 = 0.f, d11 = 0.f;
#pragma unroll
        for (int c4 = 0; c4 < 4; ++c4) {
            float4 x0 = *(const float4*)&xlds[0 * 640 + 20 * lane + c4 * 4];
            float4 x1 = *(const float4*)&xlds[1 * 640 + 20 * lane + c4 * 4];
            float4 y0 = *(const float4*)&hlds[0 * 640 + 20 * lane + c4 * 4];
            float4 y1 = *(const float4*)&hlds[1 * 640 + 20 * lane + c4 * 4];
            d00 += w16[c4*4+0]*x0.x + w16[c4*4+1]*x0.y + w16[c4*4+2]*x0.z + w16[c4*4+3]*x0.w;
            d01 += w16[c4*4+0]*x1.x + w16[c4*4+1]*x1.y + w16[c4*4+2]*x1.z + w16[c4*4+3]*x1.w;
            d10 += w16[c4*4+0]*y0.x + w16[c4*4+1]*y0.y + w16[c4*4+2]*y0.z + w16[c4*4+3]*y0.w;
            d11 += w16[c4*4+0]*y1.x + w16[c4*4+1]*y1.y + w16[c4*4+2]*y1.z + w16[c4*4+3]*y1.w;
        }
        const float biq = bih1[1536 + q * 512 + j];
        gp[0][0][q] = red32(d00) + biq; gp[0][1][q] = red32(d01) + biq;
        gp[1][0][q] = red32(d10) + biq; gp[1][1][q] = red32(d11) + biq;
    }
#pragma unroll
    for (int q = 0; q < 3; ++q) bh[q] = bhh1[1536 + q * 512 + j];

#pragma unroll
    for (int s = 0; s < 2; ++s)
        hp[s] = gru1(gp[0][s][0], gp[0][s][1], gp[0][s][2], 0.f, 0.f, 0.f, bh, 0.f);
    if (lane == 0)
#pragma unroll
        for (int s = 0; s < 2; ++s)
            __hip_atomic_store(tb1 + 1024 + s * 512 + j, hp[s],
                               __ATOMIC_RELAXED, __HIP_MEMORY_SCOPE_AGENT);
    PUBLISH(3);

    WAIT_ALL(3);
    stage1024(hlds, tb1 + 1024, tid);
    __syncthreads();
    {
        float wh3[3][16];
#pragma unroll
        for (int q = 0; q < 3; ++q) {
            const float* wp = Whh1 + WS + (size_t)(q * 512 + j) * 512 + colbase;
#pragma unroll
            for (int c4 = 0; c4 < 4; ++c4) {
                float4 v = *(const float4*)(wp + c4 * 4);
                wh3[q][c4*4+0] = v.x; wh3[q][c4*4+1] = v.y;
                wh3[q][c4*4+2] = v.z; wh3[q][c4*4+3] = v.w;
            }
        }
        float acc[3][2] = {{0.f,0.f},{0.f,0.f},{0.f,0.f}};
#pragma unroll
        for (int s = 0; s < 2; ++s) {
            const int base = s * 640 + 20 * lane;
#pragma unroll
            for (int c4 = 0; c4 < 4; ++c4) {
                float4 hv = *(const float4*)&hlds[base + c4 * 4];
#pragma unroll
                for (int q = 0; q < 3; ++q)
                    acc[q][s] += wh3[q][c4*4+0]*hv.x + wh3[q][c4*4+1]*hv.y
                               + wh3[q][c4*4+2]*hv.z + wh3[q][c4*4+3]*hv.w;
            }
        }
#pragma unroll
        for (int s = 0; s < 2; ++s) {
            float a0 = red32(acc[0][s]), a1 = red32(acc[1][s]), a2 = red32(acc[2][s]);
            hp[s] = gru1(gp[1][s][0], gp[1][s][1], gp[1][s][2], a0, a1, a2, bh, hp[s]);
        }
        if (lane == 0)
#pragma unroll
            for (int s = 0; s < 2; ++s)
                __hip_atomic_store(tb1 + 2048 + s * 512 + j, hp[s],
                                   __ATOMIC_RELAXED, __HIP_MEMORY_SCOPE_AGENT);
        PUBLISH(4);
    }

    // ================= stage C: conv + global max pool =================
    WAIT_ALL(4);
    float m4[4];
    if (wgi == 0) {
        stage1024(xlds, tb0 + 2048, tid);          // finals L0 [2][512]
        if (tid >= 256) {
            const int i = tid - 256;
            const unsigned long long* s = (const unsigned long long*)(tb1 + 2048) + i * 2;
            unsigned long long d0 = __hip_atomic_load(s + 0, __ATOMIC_RELAXED, __HIP_MEMORY_SCOPE_AGENT);
            unsigned long long d1 = __hip_atomic_load(s + 1, __ATOMIC_RELAXED, __HIP_MEMORY_SCOPE_AGENT);
            union { unsigned long long u; float2 f; } c0, c1; c0.u = d0; c1.u = d1;
            float* d = hlds + LDSP(i * 4);
            d[0] = c0.f.x; d[1] = c0.f.y; d[2] = c1.f.x; d[3] = c1.f.y;
        }
        __syncthreads();
        for (int so = 0; so < 4; ++so) {
            const int s = so >> 1, o = so & 1;
            float acc = -3.4e38f;
            if (tid < 256) {
                acc = convb[o];
                const int base = 2 * tid - 255;
                for (int k = 0; k < 512; ++k) {
                    const int pos = base + k;
                    if ((unsigned)pos < 512u) {
                        const int gi0i = s * 512 + pos;
                        acc += xlds[LDSP(gi0i)] * convw[(size_t)(o * 2 + 0) * 512 + k]
                             + hlds[LDSP(gi0i)] * convw[(size_t)(o * 2 + 1) * 512 + k];
                    }
                }
            }
            float m = acc;
            m = fmaxf(m, __shfl_xor(m, 32, 64));
            m = fmaxf(m, __shfl_xor(m, 16, 64));
            m = fmaxf(m, __shfl_xor(m, 8, 64));
            m = fmaxf(m, __shfl_xor(m, 4, 64));
            m = fmaxf(m, __shfl_xor(m, 2, 64));
            m = fmaxf(m, __shfl_xor(m, 1, 64));
            if ((tid & 63) == 0) red[tid >> 6] = m;
            __syncthreads();
            if (tid == 0) {
                float mm = red[0];
                for (int i = 1; i < 8; ++i) mm = fmaxf(mm, red[i]);
                smax[so] = mm;
            }
            __syncthreads();
        }
        if (tid == 0) {
            for (int i = 0; i < 4; ++i)
                __hip_atomic_store(Mmax + i, smax[i],
                                   __ATOMIC_RELAXED, __HIP_MEMORY_SCOPE_AGENT);
            __builtin_amdgcn_s_waitcnt(0);
            __hip_atomic_store(mf, 1u, __ATOMIC_RELAXED, __HIP_MEMORY_SCOPE_AGENT);
        }
        __syncthreads();
#pragma unroll
        for (int i = 0; i < 4; ++i) m4[i] = smax[i];
    } else {
        if (tid == 0) poll_ge(mf, 1u);
        __syncthreads();
#pragma unroll
        for (int i = 0; i < 4; ++i)
            m4[i] = __hip_atomic_load((const float*)Mmax + i, __ATOMIC_RELAXED,
                                      __HIP_MEMORY_SCOPE_AGENT);
    }

    // ================= stage D: rnn2 (T=2, gi = Mmax*Srow + bih2) =================
    {
        float wh3[3][16];
#pragma unroll
        for (int q = 0; q < 3; ++q) {
            const float* wp = Whh2 + (size_t)(q * 512 + j) * 512 + colbase;
#pragma unroll
            for (int c4 = 0; c4 < 4; ++c4) {
                float4 v = *(const float4*)(wp + c4 * 4);
                wh3[q][c4*4+0] = v.x; wh3[q][c4*4+1] = v.y;
                wh3[q][c4*4+2] = v.z; wh3[q][c4*4+3] = v.w;
            }
        }
#pragma unroll
        for (int q = 0; q < 3; ++q) {
            const float sq = Srow[q * 512 + j];
            const float biq = bih2[q * 512 + j];
#pragma unroll
            for (int s = 0; s < 2; ++s) {
                gp[0][s][q] = m4[s * 2 + 0] * sq + biq;
                gp[1][s][q] = m4[s * 2 + 1] * sq + biq;
            }
            bh[q] = bhh2[q * 512 + j];
        }
#pragma unroll
        for (int s = 0; s < 2; ++s)
            hp[s] = gru1(gp[0][s][0], gp[0][s][1], gp[0][s][2], 0.f, 0.f, 0.f, bh, 0.f);
        if (lane == 0)
#pragma unroll
            for (int s = 0; s < 2; ++s)
                __hip_atomic_store(tr + 1024 + s * 512 + j, hp[s],
                                   __ATOMIC_RELAXED, __HIP_MEMORY_SCOPE_AGENT);
        PUBLISH(5);

        WAIT_ALL(5);
        stage1024(hlds, tr + 1024, tid);
        __syncthreads();
        float acc[3][2] = {{0.f,0.f},{0.f,0.f},{0.f,0.f}};
#pragma unroll
        for (int s = 0; s < 2; ++s) {
            const int base = s * 640 + 20 * lane;
#pragma unroll
            for (int c4 = 0; c4 < 4; ++c4) {
                float4 hv = *(const float4*)&hlds[base + c4 * 4];
#pragma unroll
                for (int q = 0; q < 3; ++q)
                    acc[q][s] += wh3[q][c4*4+0]*hv.x + wh3[q][c4*4+1]*hv.y
                               + wh3[q][c4*4+2]*hv.z + wh3[q][c4*4+3]*hv.w;
            }
        }
#pragma unroll
        for (int s = 0; s < 2; ++s) {
            float a0 = red32(acc[0][s]), a1 = red32(acc[1][s]), a2 = red32(acc[2][s]);
            hp[s] = gru1(gp[1][s][0], gp[1][s][1], gp[1][s][2], a0, a1, a2, bh, hp[s]);
        }
        if (lane == 0)
#pragma unroll
            for (int s = 0; s < 2; ++s)
                __hip_atomic_store(tr + 2048 + s * 512 + j, hp[s],
                                   __ATOMIC_RELAXED, __HIP_MEMORY_SCOPE_AGENT);
        PUBLISH(6);
    }

    // ================= stage E: similarity head (WG0 only) =================
    WAIT_ALL(6);
    if (wgi != 0) return;
    stage1024(xlds, tr + 2048, tid);          // hA = [0..511], hB = [512..1023]
    __syncthreads();
    float v = 0.f;
    if (tid < 256) {
        float acc = b_bi[tid];
        for (int jj = 0; jj < 512; ++jj) {
            const float a = xlds[LDSP(jj)];
            const float b = xlds[LDSP(512 + jj)];
            acc += (a * b) * WA[(size_t)jj * 256 + tid]
                 + fabsf(a - b) * WB[(size_t)jj * 256 + tid];
        }
        v = tanhf(acc) * Wlin[tid];
    }
    v += __shfl_xor(v, 32, 64);
    v += __shfl_xor(v, 16, 64);
    v += __shfl_xor(v, 8, 64);
    v += __shfl_xor(v, 4, 64);
    v += __shfl_xor(v, 2, 64);
    v += __shfl_xor(v, 1, 64);
    if ((tid & 63) == 0) red[tid >> 6] = v;
    __syncthreads();
    if (tid == 0) {
        float ssum = blin[0];
        for (int i = 0; i < 8; ++i) ssum += red[i];
        outp[0] = 1.f / (1.f + expf(-ssum));
    }
#undef WAIT_ALL
#undef PUBLISH
}

// ---------------------------------------------------------------------------
// init: zero all flag lines; Srow[r] = sum_k Wih2[r][k] (k<128)
// ---------------------------------------------------------------------------
__global__ __launch_bounds__(256) void k_init(
    const float* __restrict__ Wih2, float* __restrict__ Srow,
    unsigned int* __restrict__ flags)   // fL0|fL1|tctr|mf = 512+512+512+16
{
    const int g = blockIdx.x * 256 + threadIdx.x;   // 0..2047
    if (g < 1536) {
        float s = 0.f;
        const float* row = Wih2 + (size_t)g * 128;
        for (int k = 0; k < 128; k += 4) {
            float4 v = *(const float4*)(row + k);
            s += v.x + v.y + v.z + v.w;
        }
        Srow[g] = s;
    }
    if (g < 1552) flags[g] = 0u;
}

// ---------------------------------------------------------------------------
extern "C" void kernel_launch(void* const* d_in, const int* in_sizes, int n_in,
                              void* d_out, int out_size, void* d_ws, size_t ws_size,
                              hipStream_t stream)
{
    const int*   sentA = (const int*)d_in[0];
    const int*   sentB = (const int*)d_in[1];
    const float* emb   = (const float*)d_in[2];
    const float* Wih1  = (const float*)d_in[3];   // [2][1536][512]
    const float* Whh1  = (const float*)d_in[4];   // [2][1536][512]
    const float* bih1  = (const float*)d_in[5];   // [2][1536]
    const float* bhh1  = (const float*)d_in[6];   // [2][1536]
    const float* convw = (const float*)d_in[7];   // [2][2][512]
    const float* convb = (const float*)d_in[8];   // [2]
    const float* Wih2  = (const float*)d_in[9];   // [1536][128]
    const float* Whh2  = (const float*)d_in[10];  // [1536][512]
    const float* bih2  = (const float*)d_in[11];  // [1536]
    const float* bhh2  = (const float*)d_in[12];  // [1536]
    const float* WA    = (const float*)d_in[13];  // [512][256]
    const float* WB    = (const float*)d_in[14];  // [512][256]
    const float* b_bi  = (const float*)d_in[15];  // [256]
    const float* Wlin  = (const float*)d_in[16];  // [1][256]
    const float* blin  = (const float*)d_in[17];  // [1]

    float* ws = (float*)d_ws;
    size_t off = 0;
    float* e2x    = ws + off; off += 2048;        // [2 sent][2 layer][512]
    float* hbuf0  = ws + off; off += 257 * 1024;
    float* hbuf1  = ws + off; off += 257 * 1024;
    float* tb0    = ws + off; off += 3 * 1024;
    float* tb1    = ws + off; off += 3 * 1024;
    float* tr     = ws + off; off += 3 * 1024;
    float* Mmax   = ws + off; off += 16;
    float* Srow   = ws + off; off += 1536;
    unsigned int* flags = (unsigned int*)(ws + off);  // 1552 u32
    unsigned int* fL0  = flags;
    unsigned int* fL1  = flags + 512;
    unsigned int* tctr = flags + 1024;
    unsigned int* mf   = flags + 1536;

    k_init<<<8, 256, 0, stream>>>(Wih2, Srow, flags);

    k_pipe<<<64, 512, 0, stream>>>(Whh1, bhh1, Wih1, bih1, emb, sentA, sentB,
                                   e2x, hbuf0, hbuf1, fL0, fL1);

    k_tail<<<32, 512, 0, stream>>>(Wih1, bih1, Whh1, bhh1, convw, convb,
                                   Whh2, bhh2, bih2, Srow, e2x,
                                   WA, WB, b_bi, Wlin, blin,
                                   tb0, tb1, tr, Mmax, tctr, mf, (float*)d_out);
}